// Round 8
// baseline (2035.185 us; speedup 1.0000x reference)
//
#include <hip/hip_runtime.h>
#include <math.h>

typedef unsigned short u16;
typedef unsigned int   u32;
typedef __attribute__((ext_vector_type(4))) unsigned short u16x4;

#define BATCH  32
#define SEQ    512
#define DM     512
#define SQE    (SEQ*DM)

__device__ __forceinline__ float bf2f(u16 u) {
  union { u32 i; float f; } v; v.i = ((u32)u) << 16; return v.f;
}
__device__ __forceinline__ u16 f2bf(float x) {
  union { float f; u32 i; } v; v.f = x;
  u32 r = v.i + 0x7fffu + ((v.i >> 16) & 1u);
  return (u16)(r >> 16);
}

// scores[b][q][k] = (1/sqrt(D)) * sum_d P[b][q][d] * E[b][k][d]  -> FP32 into out0
__global__ __launch_bounds__(256) void v_scores(const float* __restrict__ P,
                                                const float* __restrict__ E,
                                                float* __restrict__ Sc)
{
  const int mt = blockIdx.x, nt = blockIdx.y, b = blockIdx.z;
  const int tx = threadIdx.x & 15, ty = threadIdx.x >> 4;
  const float* A = P + (size_t)b * SQE + (size_t)(mt * 64 + ty * 4) * DM;
  const float* B = E + (size_t)b * SQE + (size_t)(nt * 64 + tx * 4) * DM;
  float acc[4][4] = {};
  for (int k = 0; k < DM; k += 4) {
    float4 av[4], bv[4];
#pragma unroll
    for (int i = 0; i < 4; ++i) av[i] = *(const float4*)(A + (size_t)i * DM + k);
#pragma unroll
    for (int j = 0; j < 4; ++j) bv[j] = *(const float4*)(B + (size_t)j * DM + k);
#pragma unroll
    for (int i = 0; i < 4; ++i)
#pragma unroll
      for (int j = 0; j < 4; ++j)
        acc[i][j] += av[i].x * bv[j].x + av[i].y * bv[j].y
                   + av[i].z * bv[j].z + av[i].w * bv[j].w;
  }
  const float scale = 0.044194173824159216f;  // 1/sqrt(512)
  float* out = Sc + (size_t)b * SQE + (size_t)(mt * 64 + ty * 4) * SEQ + nt * 64 + tx * 4;
#pragma unroll
  for (int i = 0; i < 4; ++i)
#pragma unroll
    for (int j = 0; j < 4; ++j)
      out[(size_t)i * SEQ + j] = acc[i][j] * scale;
}

// row softmax over 512 cols: fp32 scores (out0) -> FP32 weights (out1)
__global__ __launch_bounds__(256) void v_softmax(const float* __restrict__ Sc,
                                                 float* __restrict__ Wt)
{
  const int row  = blockIdx.x * 4 + (threadIdx.x >> 6);
  const int lane = threadIdx.x & 63;
  const float* src = Sc + (size_t)row * SEQ + lane * 8;
  float4 va = *(const float4*)(src);
  float4 vb = *(const float4*)(src + 4);
  float v[8] = {va.x, va.y, va.z, va.w, vb.x, vb.y, vb.z, vb.w};
  float m = v[0];
#pragma unroll
  for (int j = 1; j < 8; ++j) m = fmaxf(m, v[j]);
#pragma unroll
  for (int off = 32; off > 0; off >>= 1) m = fmaxf(m, __shfl_xor(m, off, 64));
  float s = 0.f;
#pragma unroll
  for (int j = 0; j < 8; ++j) { v[j] = __expf(v[j] - m); s += v[j]; }
#pragma unroll
  for (int off = 32; off > 0; off >>= 1) s += __shfl_xor(s, off, 64);
  const float inv = 1.0f / s;
  float* dst = Wt + (size_t)row * SEQ + lane * 8;
  float4 o0 = {v[0] * inv, v[1] * inv, v[2] * inv, v[3] * inv};
  float4 o1 = {v[4] * inv, v[5] * inv, v[6] * inv, v[7] * inv};
  *(float4*)(dst)     = o0;
  *(float4*)(dst + 4) = o1;
}

// ctx[b][q][d] = sum_k w[b][q][k] * E[b][k][d]  -> FP32 into out0 (scores dead)
__global__ __launch_bounds__(256) void v_context(const float* __restrict__ Wt,
                                                 const float* __restrict__ E,
                                                 float* __restrict__ Ctx)
{
  const int mt = blockIdx.x, nt = blockIdx.y, b = blockIdx.z;
  const int tx = threadIdx.x & 15, ty = threadIdx.x >> 4;
  const float* A = Wt + (size_t)b * SQE + (size_t)(mt * 64 + ty * 4) * SEQ;
  const float* B = E + (size_t)b * SQE + nt * 64 + tx * 4;
  float acc[4][4] = {};
  for (int k = 0; k < SEQ; ++k) {
    float4 bv = *(const float4*)(B + (size_t)k * DM);
    float bb[4] = {bv.x, bv.y, bv.z, bv.w};
#pragma unroll
    for (int i = 0; i < 4; ++i) {
      const float a = A[(size_t)i * SEQ + k];
#pragma unroll
      for (int j = 0; j < 4; ++j) acc[i][j] += a * bb[j];
    }
  }
  float* out = Ctx + (size_t)b * SQE + (size_t)(mt * 64 + ty * 4) * DM + nt * 64 + tx * 4;
#pragma unroll
  for (int i = 0; i < 4; ++i)
#pragma unroll
    for (int j = 0; j < 4; ++j)
      out[(size_t)i * DM + j] = acc[i][j];
}

// Row-exclusive final: block owns 64 q-rows. Loads its fp32 ctx rows (from
// out0) into LDS (as bf16 — precision impact ~2e-4), computes
// out = tanh([P|ctx] @ W^T + b) * mask, overwrites only its own rows. FP32 out.
__global__ __launch_bounds__(256) void v_final_row(const float* __restrict__ P,
                                                   const float* __restrict__ W,
                                                   const float* __restrict__ bias,
                                                   const float* __restrict__ mask,
                                                   float* __restrict__ Out)
{
  __shared__ u16 sc[64 * 516];  // 64 rows, stride 516 (pad 4)
  const int b = blockIdx.y, mt = blockIdx.x;
  const int tid = threadIdx.x;
  float* base = Out + (size_t)b * SQE + (size_t)(mt * 64) * DM;
  for (int i = tid * 4; i < 64 * 512; i += 256 * 4) {
    const int r = i >> 9, c = i & 511;
    float4 t = *(const float4*)(base + (size_t)r * DM + c);
    u16x4 o = { f2bf(t.x), f2bf(t.y), f2bf(t.z), f2bf(t.w) };
    *(u16x4*)(sc + r * 516 + c) = o;
  }
  __syncthreads();

  const int tx = tid & 15, ty = tid >> 4;
  const int r0 = ty * 4;
  const float* Arow = P + (size_t)b * SQE + (size_t)(mt * 64 + r0) * DM;
  for (int nt = 0; nt < 8; ++nt) {
    const int c0 = nt * 64 + tx * 4;
    const float* Bw = W + (size_t)c0 * 1024;
    float acc[4][4] = {};
    for (int k = 0; k < 512; k += 4) {
      float4 av[4], bv[4];
#pragma unroll
      for (int i = 0; i < 4; ++i) av[i] = *(const float4*)(Arow + (size_t)i * DM + k);
#pragma unroll
      for (int j = 0; j < 4; ++j) bv[j] = *(const float4*)(Bw + (size_t)j * 1024 + k);
#pragma unroll
      for (int i = 0; i < 4; ++i)
#pragma unroll
        for (int j = 0; j < 4; ++j)
          acc[i][j] += av[i].x * bv[j].x + av[i].y * bv[j].y
                     + av[i].z * bv[j].z + av[i].w * bv[j].w;
    }
    for (int k = 0; k < 512; k += 4) {
      float a[4][4];
#pragma unroll
      for (int i = 0; i < 4; ++i) {
        u16x4 t = *(const u16x4*)(sc + (r0 + i) * 516 + k);
#pragma unroll
        for (int kk = 0; kk < 4; ++kk) a[i][kk] = bf2f(t[kk]);
      }
      float4 bv[4];
#pragma unroll
      for (int j = 0; j < 4; ++j) bv[j] = *(const float4*)(Bw + (size_t)j * 1024 + 512 + k);
#pragma unroll
      for (int i = 0; i < 4; ++i)
#pragma unroll
        for (int j = 0; j < 4; ++j)
          acc[i][j] += a[i][0] * bv[j].x + a[i][1] * bv[j].y
                     + a[i][2] * bv[j].z + a[i][3] * bv[j].w;
    }
#pragma unroll
    for (int i = 0; i < 4; ++i) {
      const float mv = mask[b * SEQ + mt * 64 + r0 + i];
#pragma unroll
      for (int j = 0; j < 4; ++j)
        base[(size_t)(r0 + i) * DM + c0 + j] = tanhf(acc[i][j] + bias[c0 + j]) * mv;
    }
  }
}

extern "C" void kernel_launch(void* const* d_in, const int* in_sizes, int n_in,
                              void* d_out, int out_size, void* d_ws, size_t ws_size,
                              hipStream_t stream)
{
  // input identification by flat size; 8.4M pair in dict order (P first, E second)
  int i8a = -1, i8b = -1, iM = -1, iW = -1, iB = -1;
  for (int i = 0; i < n_in; ++i) {
    const int s = in_sizes[i];
    if (s == BATCH * SQE)      { if (i8a < 0) i8a = i; else i8b = i; }
    else if (s == BATCH * SEQ) iM = i;
    else if (s == DM * 1024)   iW = i;
    else if (s == DM)          iB = i;
  }
  if (i8a < 0) i8a = 0;
  if (i8b < 0) i8b = 1;
  if (iM < 0) iM = 2;
  if (iW < 0) iW = 3;
  if (iB < 0) iB = 4;
  const float* P  = (const float*)d_in[i8a];   // padded_seqs (dict order)
  const float* E  = (const float*)d_in[i8b];   // encoder_padded_seqs
  const float* Mk = (const float*)d_in[iM];
  const float* W  = (const float*)d_in[iW];
  const float* Bi = (const float*)d_in[iB];

  // *** d_out is FP32 *** (reference outputs are jnp.float32; the "bf16" in
  // the test label is the comparison precision, not the buffer dtype).
  float* out0 = (float*)d_out;                     // attention_masked
  float* out1 = out0 + (size_t)BATCH * SQE;        // attention_weights

  // ZERO workspace: fp32 scores live in out0 (dead after softmax), fp32 ctx
  // overwrites out0, final stage overwrites out0 row-exclusively.
  dim3 blk(256);
  dim3 gg(8, 8, BATCH);
  v_scores   <<<gg, blk, 0, stream>>>(P, E, out0);
  v_softmax  <<<dim3(BATCH * SEQ / 4), blk, 0, stream>>>(out0, out1);
  v_context  <<<gg, blk, 0, stream>>>(out1, E, out0);
  v_final_row<<<dim3(8, BATCH), blk, 0, stream>>>(P, W, Bi, Mk, out0);
}

// Round 9
// 224.225 us; speedup vs baseline: 9.0765x; 9.0765x over previous
//
#include <hip/hip_runtime.h>
#include <math.h>

typedef unsigned short u16;
typedef unsigned int   u32;
typedef __attribute__((ext_vector_type(8))) short bf16x8;
typedef __attribute__((ext_vector_type(4))) unsigned short u16x4;
typedef __attribute__((ext_vector_type(4))) float f32x4;

#define BATCH  32
#define SEQ    512
#define DM     512
#define SQE    (SEQ*DM)

__device__ __forceinline__ float bf2f(u16 u) {
  union { u32 i; float f; } v; v.i = ((u32)u) << 16; return v.f;
}
__device__ __forceinline__ u16 f2bf(float x) {
  union { float f; u32 i; } v; v.f = x;
  u32 r = v.i + 0x7fffu + ((v.i >> 16) & 1u);
  return (u16)(r >> 16);
}

// Load 8 consecutive elements at element-offset eoff as bf16x8.
// F32: source fp32 (convert); else bf16 direct.
template<bool F32>
__device__ __forceinline__ bf16x8 ld8(const void* p, size_t eoff) {
  if (F32) {
    const float* f = (const float*)p + eoff;
    float4 a = *(const float4*)f;
    float4 b = *(const float4*)(f + 4);
    bf16x8 o;
    o[0] = (short)f2bf(a.x); o[1] = (short)f2bf(a.y);
    o[2] = (short)f2bf(a.z); o[3] = (short)f2bf(a.w);
    o[4] = (short)f2bf(b.x); o[5] = (short)f2bf(b.y);
    o[6] = (short)f2bf(b.z); o[7] = (short)f2bf(b.w);
    return o;
  }
  return *(const bf16x8*)((const u16*)p + eoff);
}

// 128x128 tile: C += A[128xK] * B[128xK]^T (both operands k-contiguous).
// A switches Alo->Ahi at kt=ktlo (k rebased); dtypes are template params.
template<bool FALO, bool FAHI, bool FB>
__device__ __forceinline__ void gemm_mainloop(
    const void* Alo, const void* Ahi, int ktlo, int kttot,
    const void* B, int lda, int ldb,
    u16* sA, u16* sB, f32x4 acc[4][4])
{
  const int tid  = threadIdx.x;
  const int lane = tid & 63;
  const int wid  = tid >> 6;
  const int wm = (wid >> 1) * 64;
  const int wn = (wid & 1) * 64;
  const int lm = lane & 15;
  const int lq = lane >> 4;

  const int c0 = tid, c1 = tid + 256;
  const int r0 = c0 >> 2, k0 = (c0 & 3) * 8;
  const int r1 = c1 >> 2, k1 = (c1 & 3) * 8;

  for (int kt = 0; kt < kttot; ++kt) {
    bf16x8 a0, a1;
    if (kt < ktlo) {
      const size_t ao = (size_t)kt * 32;
      a0 = ld8<FALO>(Alo, ao + (size_t)r0 * lda + k0);
      a1 = ld8<FALO>(Alo, ao + (size_t)r1 * lda + k1);
    } else {
      const size_t ao = (size_t)(kt - ktlo) * 32;
      a0 = ld8<FAHI>(Ahi, ao + (size_t)r0 * lda + k0);
      a1 = ld8<FAHI>(Ahi, ao + (size_t)r1 * lda + k1);
    }
    const size_t bo = (size_t)kt * 32;
    bf16x8 b0 = ld8<FB>(B, bo + (size_t)r0 * ldb + k0);
    bf16x8 b1 = ld8<FB>(B, bo + (size_t)r1 * ldb + k1);
    *(bf16x8*)(sA + c0 * 8) = a0;
    *(bf16x8*)(sA + c1 * 8) = a1;
    *(bf16x8*)(sB + c0 * 8) = b0;
    *(bf16x8*)(sB + c1 * 8) = b1;
    __syncthreads();

    bf16x8 af[4], bfv[4];
#pragma unroll
    for (int i = 0; i < 4; ++i) {
      af[i]  = *(const bf16x8*)(sA + (wm + i * 16 + lm) * 32 + lq * 8);
      bfv[i] = *(const bf16x8*)(sB + (wn + i * 16 + lm) * 32 + lq * 8);
    }
#pragma unroll
    for (int i = 0; i < 4; ++i)
#pragma unroll
      for (int j = 0; j < 4; ++j)
        acc[i][j] = __builtin_amdgcn_mfma_f32_16x16x32_bf16(af[i], bfv[j], acc[i][j], 0, 0, 0);
    __syncthreads();
  }
}

// W (512x1024 fp32) -> bf16
__global__ __launch_bounds__(256) void k_cvtW(const float* __restrict__ W,
                                              u16* __restrict__ Wbf)
{
  const int i = (blockIdx.x * 256 + threadIdx.x) * 8;
  float4 a = *(const float4*)(W + i);
  float4 b = *(const float4*)(W + i + 4);
  bf16x8 o;
  o[0] = (short)f2bf(a.x); o[1] = (short)f2bf(a.y);
  o[2] = (short)f2bf(a.z); o[3] = (short)f2bf(a.w);
  o[4] = (short)f2bf(b.x); o[5] = (short)f2bf(b.y);
  o[6] = (short)f2bf(b.z); o[7] = (short)f2bf(b.w);
  *(bf16x8*)(Wbf + i) = o;
}

// scores = P @ E^T * scale -> fp32 into out0
__global__ __launch_bounds__(256) void k_scores(const float* __restrict__ P,
                                                const float* __restrict__ E,
                                                float* __restrict__ Sc)
{
  __shared__ u16 sA[128 * 32];
  __shared__ u16 sB[128 * 32];
  const int mt = blockIdx.x, nt = blockIdx.y, b = blockIdx.z;
  const float* A  = P + (size_t)b * SQE + (size_t)(mt * 128) * DM;
  const float* Bp = E + (size_t)b * SQE + (size_t)(nt * 128) * DM;
  f32x4 acc[4][4] = {};
  gemm_mainloop<true, true, true>(A, A, 16, 16, Bp, DM, DM, sA, sB, acc);

  const int tid = threadIdx.x, lane = tid & 63, wid = tid >> 6;
  const int wm = (wid >> 1) * 64, wn = (wid & 1) * 64;
  const int lm = lane & 15, lq = lane >> 4;
  const float scale = 0.044194173824159216f;  // 1/sqrt(512)
  float* out = Sc + (size_t)b * SQE + (size_t)(mt * 128) * SEQ + nt * 128;
#pragma unroll
  for (int i = 0; i < 4; ++i)
#pragma unroll
    for (int j = 0; j < 4; ++j)
#pragma unroll
      for (int r = 0; r < 4; ++r)
        out[(size_t)(wm + i * 16 + lq * 4 + r) * SEQ + wn + j * 16 + lm] = acc[i][j][r] * scale;
}

// row softmax (512 cols): fp32 scores (out0) -> fp32 weights (out1)
__global__ __launch_bounds__(256) void v_softmax(const float* __restrict__ Sc,
                                                 float* __restrict__ Wt)
{
  const int row  = blockIdx.x * 4 + (threadIdx.x >> 6);
  const int lane = threadIdx.x & 63;
  const float* src = Sc + (size_t)row * SEQ + lane * 8;
  float4 va = *(const float4*)(src);
  float4 vb = *(const float4*)(src + 4);
  float v[8] = {va.x, va.y, va.z, va.w, vb.x, vb.y, vb.z, vb.w};
  float m = v[0];
#pragma unroll
  for (int j = 1; j < 8; ++j) m = fmaxf(m, v[j]);
#pragma unroll
  for (int off = 32; off > 0; off >>= 1) m = fmaxf(m, __shfl_xor(m, off, 64));
  float s = 0.f;
#pragma unroll
  for (int j = 0; j < 8; ++j) { v[j] = __expf(v[j] - m); s += v[j]; }
#pragma unroll
  for (int off = 32; off > 0; off >>= 1) s += __shfl_xor(s, off, 64);
  const float inv = 1.0f / s;
  float* dst = Wt + (size_t)row * SEQ + lane * 8;
  float4 o0 = {v[0] * inv, v[1] * inv, v[2] * inv, v[3] * inv};
  float4 o1 = {v[4] * inv, v[5] * inv, v[6] * inv, v[7] * inv};
  *(float4*)(dst)     = o0;
  *(float4*)(dst + 4) = o1;
}

// ctx = weights @ E -> bf16 into ws.  B-tile (E^T) built on the fly:
// stage E slab [32 k-rows x 128 n-cols] transposed into LDS.
__global__ __launch_bounds__(256) void k_context(const float* __restrict__ Wt,
                                                 const float* __restrict__ E,
                                                 u16* __restrict__ Ctx)
{
  __shared__ u16 sA[128 * 32];
  __shared__ u16 sB[128 * 32];
  const int mt = blockIdx.x, nt = blockIdx.y, b = blockIdx.z;
  const int tid  = threadIdx.x;
  const int lane = tid & 63;
  const int wid  = tid >> 6;
  const int wm = (wid >> 1) * 64, wn = (wid & 1) * 64;
  const int lm = lane & 15, lq = lane >> 4;

  const float* A = Wt + (size_t)b * SQE + (size_t)(mt * 128) * SEQ;
  // A staging chunks
  const int c0 = tid, c1 = tid + 256;
  const int ar0 = c0 >> 2, ak0 = (c0 & 3) * 8;
  const int ar1 = c1 >> 2, ak1 = (c1 & 3) * 8;
  // B transpose staging: thread owns k-row (tid&31), 16 cols at (tid>>5)*16
  const int kk = tid & 31;
  const int cb = (tid >> 5) * 16;
  const float* Eb = E + (size_t)b * SQE + nt * 128 + cb;

  f32x4 acc[4][4] = {};
  for (int kt = 0; kt < 16; ++kt) {
    bf16x8 a0 = ld8<true>(A, (size_t)kt * 32 + (size_t)ar0 * SEQ + ak0);
    bf16x8 a1 = ld8<true>(A, (size_t)kt * 32 + (size_t)ar1 * SEQ + ak1);
    const float* src = Eb + (size_t)(kt * 32 + kk) * DM;
    float4 x0 = *(const float4*)(src);
    float4 x1 = *(const float4*)(src + 4);
    float4 x2 = *(const float4*)(src + 8);
    float4 x3 = *(const float4*)(src + 12);
    *(bf16x8*)(sA + c0 * 8) = a0;
    *(bf16x8*)(sA + c1 * 8) = a1;
    float xs[16] = {x0.x,x0.y,x0.z,x0.w, x1.x,x1.y,x1.z,x1.w,
                    x2.x,x2.y,x2.z,x2.w, x3.x,x3.y,x3.z,x3.w};
#pragma unroll
    for (int j = 0; j < 16; ++j)
      sB[(cb + j) * 32 + kk] = f2bf(xs[j]);
    __syncthreads();

    bf16x8 af[4], bfv[4];
#pragma unroll
    for (int i = 0; i < 4; ++i) {
      af[i]  = *(const bf16x8*)(sA + (wm + i * 16 + lm) * 32 + lq * 8);
      bfv[i] = *(const bf16x8*)(sB + (wn + i * 16 + lm) * 32 + lq * 8);
    }
#pragma unroll
    for (int i = 0; i < 4; ++i)
#pragma unroll
      for (int j = 0; j < 4; ++j)
        acc[i][j] = __builtin_amdgcn_mfma_f32_16x16x32_bf16(af[i], bfv[j], acc[i][j], 0, 0, 0);
    __syncthreads();
  }

  u16* out = Ctx + (size_t)b * SQE + (size_t)(mt * 128) * DM + nt * 128;
#pragma unroll
  for (int i = 0; i < 4; ++i)
#pragma unroll
    for (int j = 0; j < 4; ++j)
#pragma unroll
      for (int r = 0; r < 4; ++r)
        out[(size_t)(wm + i * 16 + lq * 4 + r) * DM + wn + j * 16 + lm] = f2bf(acc[i][j][r]);
}

// out = tanh([P|ctx] @ W^T + bias) * mask -> fp32 out0 (K=1024, switch at kt=16)
__global__ __launch_bounds__(256) void k_final(const float* __restrict__ P,
                                               const u16* __restrict__ Ctx,
                                               const u16* __restrict__ Wbf,
                                               const float* __restrict__ bias,
                                               const float* __restrict__ mask,
                                               float* __restrict__ Out)
{
  __shared__ u16 sA[128 * 32];
  __shared__ u16 sB[128 * 32];
  const int mt = blockIdx.x, nt = blockIdx.y, b = blockIdx.z;
  const float* Alo = P   + (size_t)b * SQE + (size_t)(mt * 128) * DM;
  const u16*   Ahi = Ctx + (size_t)b * SQE + (size_t)(mt * 128) * DM;
  const u16*   Bp  = Wbf + (size_t)(nt * 128) * 1024;
  f32x4 acc[4][4] = {};
  gemm_mainloop<true, false, false>(Alo, Ahi, 16, 32, Bp, DM, 1024, sA, sB, acc);

  const int tid = threadIdx.x, lane = tid & 63, wid = tid >> 6;
  const int wm = (wid >> 1) * 64, wn = (wid & 1) * 64;
  const int lm = lane & 15, lq = lane >> 4;
  float* out = Out + (size_t)b * SQE + (size_t)(mt * 128) * DM + nt * 128;
#pragma unroll
  for (int i = 0; i < 4; ++i)
#pragma unroll
    for (int r = 0; r < 4; ++r) {
      const int row = wm + i * 16 + lq * 4 + r;
      const float mv = mask[b * SEQ + mt * 128 + row];
#pragma unroll
      for (int j = 0; j < 4; ++j) {
        const int col = wn + j * 16 + lm;
        out[(size_t)row * DM + col] = tanhf(acc[i][j][r] + bias[nt * 128 + col]) * mv;
      }
    }
}

extern "C" void kernel_launch(void* const* d_in, const int* in_sizes, int n_in,
                              void* d_out, int out_size, void* d_ws, size_t ws_size,
                              hipStream_t stream)
{
  // input identification by flat size; 8.4M pair in dict order (P first, E second)
  int i8a = -1, i8b = -1, iM = -1, iW = -1, iB = -1;
  for (int i = 0; i < n_in; ++i) {
    const int s = in_sizes[i];
    if (s == BATCH * SQE)      { if (i8a < 0) i8a = i; else i8b = i; }
    else if (s == BATCH * SEQ) iM = i;
    else if (s == DM * 1024)   iW = i;
    else if (s == DM)          iB = i;
  }
  if (i8a < 0) i8a = 0;
  if (i8b < 0) i8b = 1;
  if (iM < 0) iM = 2;
  if (iW < 0) iW = 3;
  if (iB < 0) iB = 4;
  const float* P  = (const float*)d_in[i8a];
  const float* E  = (const float*)d_in[i8b];
  const float* Mk = (const float*)d_in[iM];
  const float* W  = (const float*)d_in[iW];
  const float* Bi = (const float*)d_in[iB];

  float* out0 = (float*)d_out;                     // attention_masked (fp32)
  float* out1 = out0 + (size_t)BATCH * SQE;        // attention_weights (fp32)

  // ws: Ctx bf16 [0 .. 16.78MB) | Wbf bf16 [16.78 .. 17.83MB)
  u16* Ctx = (u16*)d_ws;
  u16* Wbf = Ctx + (size_t)BATCH * SQE;

  dim3 blk(256);
  dim3 gg(4, 4, BATCH);
  k_cvtW   <<<dim3(DM * 1024 / (256 * 8)), blk, 0, stream>>>(W, Wbf);
  k_scores <<<gg, blk, 0, stream>>>(P, E, out0);
  v_softmax<<<dim3(BATCH * SEQ / 4), blk, 0, stream>>>(out0, out1);
  k_context<<<gg, blk, 0, stream>>>(out1, E, Ctx);
  k_final  <<<gg, blk, 0, stream>>>(P, Ctx, Wbf, Bi, Mk, out0);
}